// Round 3
// baseline (449.934 us; speedup 1.0000x reference)
//
#include <hip/hip_runtime.h>
#include <hip/hip_bf16.h>

#define B_   2
#define N_   384
#define DIM_ 256
#define H_   4
#define DH_  64
#define PD_  128
#define ED_  16

typedef _Float16 v8h __attribute__((ext_vector_type(8)));
typedef _Float16 v2h __attribute__((ext_vector_type(2)));
typedef float    v4f __attribute__((ext_vector_type(4)));

__device__ __forceinline__ float gelu_(float x) {
    return 0.5f * x * (1.0f + erff(x * 0.70710678118654752f));
}

// full-block reduction over 256 threads (4 waves)
__device__ __forceinline__ float block_reduce256(float v, float* red) {
    #pragma unroll
    for (int o = 32; o > 0; o >>= 1) v += __shfl_xor(v, o, 64);
    __syncthreads();
    if ((threadIdx.x & 63) == 0) red[threadIdx.x >> 6] = v;
    __syncthreads();
    return red[0] + red[1] + red[2] + red[3];
}

// batched float4 block reduction over 384 threads (6 waves). red holds 16 float4.
// slot alternation (0/1) makes one barrier per reduce safe.
__device__ __forceinline__ float4 block_reduce4(float4 v, bool ismax, float4* red, int slot) {
    #pragma unroll
    for (int o = 32; o > 0; o >>= 1) {
        float x = __shfl_xor(v.x, o), y = __shfl_xor(v.y, o);
        float z = __shfl_xor(v.z, o), w = __shfl_xor(v.w, o);
        if (ismax) { v.x = fmaxf(v.x, x); v.y = fmaxf(v.y, y); v.z = fmaxf(v.z, z); v.w = fmaxf(v.w, w); }
        else       { v.x += x; v.y += y; v.z += z; v.w += w; }
    }
    if ((threadIdx.x & 63) == 0) red[slot * 8 + (threadIdx.x >> 6)] = v;
    __syncthreads();
    float4 r = red[slot * 8];
    #pragma unroll
    for (int w2 = 1; w2 < 6; w2++) {
        float4 o = red[slot * 8 + w2];
        if (ismax) { r.x = fmaxf(r.x, o.x); r.y = fmaxf(r.y, o.y); r.z = fmaxf(r.z, o.z); r.w = fmaxf(r.w, o.w); }
        else       { r.x += o.x; r.y += o.y; r.z += o.z; r.w += o.w; }
    }
    return r;
}

// ---------- K1: LayerNorm + QKV + gates ----------
__global__ __launch_bounds__(256) void eq_k1(
    const float* __restrict__ feats, const float* __restrict__ gamma,
    const float* __restrict__ w_qkv, const float* __restrict__ w_gate,
    const float* __restrict__ b_gate,
    float* __restrict__ q, float* __restrict__ kT, float* __restrict__ v,
    float* __restrict__ og, float* __restrict__ rg) {
    int row = blockIdx.x;           // b*N + n
    int b = row / N_, n = row - b * N_;
    int t = threadIdx.x;
    __shared__ float xs[DIM_];
    __shared__ float red[4];
    float f = feats[(long)row * DIM_ + t];
    float mean = block_reduce256(f, red) * (1.0f / DIM_);
    float d = f - mean;
    float var = block_reduce256(d * d, red) * (1.0f / DIM_);
    float x = d * rsqrtf(var + 1e-5f) * gamma[t];
    xs[t] = x;
    __syncthreads();
    float a0 = 0, a1 = 0, a2 = 0;
    for (int c = 0; c < DIM_; c++) {
        float xc = xs[c];
        const float* wr = w_qkv + (long)c * 768;
        a0 += xc * wr[t];
        a1 += xc * wr[t + 256];
        a2 += xc * wr[t + 512];
    }
    int h = t >> 6, dd = t & 63;
    q[((b * H_ + h) * N_ + n) * DH_ + dd]  = a0 * 0.125f;      // dh^-0.5 pre-applied
    kT[((b * H_ + h) * DH_ + dd) * N_ + n] = a1;               // transposed for coalesced reads
    v[((b * H_ + h) * N_ + n) * DH_ + dd]  = a2;
    if (t < 8) {
        float acc = b_gate[t];
        for (int c = 0; c < DIM_; c++) acc += xs[c] * w_gate[c * 8 + t];
        float g = 1.0f / (1.0f + __expf(-acc));
        if (t < 4) og[(b * H_ + t) * N_ + n] = g;
        else       rg[(b * H_ + (t - 4)) * N_ + n] = g;
    }
}

// ---------- K2: position-bias MLP as fused MFMA GEMM ----------
// Tile = 128 pairs. 4 waves split the 128 output channels (32 cols each).
// Weights live in VGPRs as B-fragments; layers are textually duplicated
// (DO_LAYER macro) so all array indices are compile-time -> no scratch spill.
// Apply-phase writes use lane^1 exchange + packed v2h (2-way banks = free).
#define DO_LAYER(BF, bsA_, bsB_, gA_, gB_, bA_, bB_)                              \
{                                                                                  \
    v4f acc[8][2];                                                                 \
    _Pragma("unroll")                                                              \
    for (int mt = 0; mt < 8; mt++) {                                               \
        const _Float16* hr = &hS[(mt * 16 + l15) * 136 + quad * 8];                \
        v8h a0 = *(const v8h*)&hr[0];                                              \
        v8h a1 = *(const v8h*)&hr[32];                                             \
        v8h a2 = *(const v8h*)&hr[64];                                             \
        v8h a3 = *(const v8h*)&hr[96];                                             \
        {                                                                          \
            v4f c = {bsA_, bsA_, bsA_, bsA_};                                      \
            c = __builtin_amdgcn_mfma_f32_16x16x32_f16(a0, BF##_00, c, 0, 0, 0);   \
            c = __builtin_amdgcn_mfma_f32_16x16x32_f16(a1, BF##_01, c, 0, 0, 0);   \
            c = __builtin_amdgcn_mfma_f32_16x16x32_f16(a2, BF##_02, c, 0, 0, 0);   \
            c = __builtin_amdgcn_mfma_f32_16x16x32_f16(a3, BF##_03, c, 0, 0, 0);   \
            acc[mt][0] = c;                                                        \
        }                                                                          \
        {                                                                          \
            v4f c = {bsB_, bsB_, bsB_, bsB_};                                      \
            c = __builtin_amdgcn_mfma_f32_16x16x32_f16(a0, BF##_10, c, 0, 0, 0);   \
            c = __builtin_amdgcn_mfma_f32_16x16x32_f16(a1, BF##_11, c, 0, 0, 0);   \
            c = __builtin_amdgcn_mfma_f32_16x16x32_f16(a2, BF##_12, c, 0, 0, 0);   \
            c = __builtin_amdgcn_mfma_f32_16x16x32_f16(a3, BF##_13, c, 0, 0, 0);   \
            acc[mt][1] = c;                                                        \
        }                                                                          \
    }                                                                              \
    _Pragma("unroll")                                                              \
    for (int mt = 0; mt < 8; mt++) {                                               \
        float s[4], sq[4];                                                         \
        _Pragma("unroll")                                                          \
        for (int rg2 = 0; rg2 < 4; rg2++) {                                        \
            float v0 = acc[mt][0][rg2], v1 = acc[mt][1][rg2];                      \
            s[rg2] = v0 + v1; sq[rg2] = v0 * v0 + v1 * v1;                         \
        }                                                                          \
        _Pragma("unroll")                                                          \
        for (int o = 1; o < 16; o <<= 1) {                                         \
            _Pragma("unroll")                                                      \
            for (int rg2 = 0; rg2 < 4; rg2++) {                                    \
                s[rg2]  += __shfl_xor(s[rg2], o);                                  \
                sq[rg2] += __shfl_xor(sq[rg2], o);                                 \
            }                                                                      \
        }                                                                          \
        if (l15 == 0) {                                                            \
            _Pragma("unroll")                                                      \
            for (int rg2 = 0; rg2 < 4; rg2++) {                                    \
                int row2 = mt * 16 + quad * 4 + rg2;                               \
                *(float2*)&prt[(row2 * 4 + wv) * 2] = make_float2(s[rg2], sq[rg2]);\
            }                                                                      \
        }                                                                          \
    }                                                                              \
    __syncthreads();                                                               \
    if (t < 128) {                                                                 \
        float s = 0.f, sq = 0.f;                                                   \
        _Pragma("unroll")                                                          \
        for (int w2 = 0; w2 < 4; w2++) {                                           \
            float2 pv = *(const float2*)&prt[(t * 4 + w2) * 2];                    \
            s += pv.x; sq += pv.y;                                                 \
        }                                                                          \
        float mean = s * (1.f / 128.f);                                            \
        mi[t * 2] = mean;                                                          \
        mi[t * 2 + 1] = rsqrtf(sq * (1.f / 128.f) - mean * mean + 1e-5f);          \
    }                                                                              \
    __syncthreads();                                                               \
    _Pragma("unroll")                                                              \
    for (int mt = 0; mt < 8; mt++) {                                               \
        float y0[4], y1[4];                                                        \
        _Pragma("unroll")                                                          \
        for (int rg2 = 0; rg2 < 4; rg2++) {                                        \
            int row2 = mt * 16 + quad * 4 + rg2;                                   \
            float2 m2 = *(const float2*)&mi[row2 * 2];                             \
            float a = (acc[mt][0][rg2] - m2.x) * m2.y * gA_ + bA_;                 \
            float b = (acc[mt][1][rg2] - m2.x) * m2.y * gB_ + bB_;                 \
            y0[rg2] = a / (1.f + __expf(-a));                                      \
            y1[rg2] = b / (1.f + __expf(-b));                                      \
        }                                                                          \
        float o0[4], o1[4];                                                        \
        _Pragma("unroll")                                                          \
        for (int rg2 = 0; rg2 < 4; rg2++) {                                        \
            o0[rg2] = __shfl_xor(y0[rg2], 1);                                      \
            o1[rg2] = __shfl_xor(y1[rg2], 1);                                      \
        }                                                                          \
        const int par = lane & 1;                                                  \
        int rowA = mt * 16 + quad * 4 + (par ? 2 : 0);                             \
        float A0lo = par ? o0[2] : y0[0], A0hi = par ? y0[2] : o0[0];              \
        float B0lo = par ? o0[3] : y0[1], B0hi = par ? y0[3] : o0[1];              \
        float A1lo = par ? o1[2] : y1[0], A1hi = par ? y1[2] : o1[0];              \
        float B1lo = par ? o1[3] : y1[1], B1hi = par ? y1[3] : o1[1];              \
        *(v2h*)&hS[rowA * 136 + colp]            = (v2h){(_Float16)A0lo, (_Float16)A0hi}; \
        *(v2h*)&hS[(rowA + 1) * 136 + colp]      = (v2h){(_Float16)B0lo, (_Float16)B0hi}; \
        *(v2h*)&hS[rowA * 136 + colp + 16]       = (v2h){(_Float16)A1lo, (_Float16)A1hi}; \
        *(v2h*)&hS[(rowA + 1) * 136 + colp + 16] = (v2h){(_Float16)B1lo, (_Float16)B1hi}; \
    }                                                                              \
    __syncthreads();                                                               \
}

__global__ __launch_bounds__(256, 2) void eq_k2(
    const float* __restrict__ coors,
    const float* __restrict__ w0, const float* __restrict__ b0,
    const float* __restrict__ g0, const float* __restrict__ be0,
    const float* __restrict__ W1g, const float* __restrict__ b1,
    const float* __restrict__ g1, const float* __restrict__ be1,
    const float* __restrict__ W2g, const float* __restrict__ b2,
    const float* __restrict__ g2, const float* __restrict__ be2,
    const float* __restrict__ wqk, const float* __restrict__ bqk,
    _Float16* __restrict__ pout, float* __restrict__ qkpos) {

    __shared__ _Float16 hS[128 * 136];    // 34816 B (h tile / weight-staging)
    __shared__ float prt[128 * 4 * 2];
    __shared__ float mi[128 * 2];
    __shared__ float distS[128];
    __shared__ float prm[1280];           // w0,b0,g0,be0,b1,g1,be1,b2,g2,be2
    __shared__ _Float16 wqT[16 * 128];

    const int t = threadIdx.x;
    const int lane = t & 63, wv = t >> 6;
    const int l15 = lane & 15, quad = lane >> 4;
    const int col0 = wv * 32 + l15, col1 = col0 + 16;
    const int colp = wv * 32 + (l15 & ~1);

    for (int i2 = t; i2 < 128; i2 += 256) {
        prm[i2] = w0[i2]; prm[128 + i2] = b0[i2]; prm[256 + i2] = g0[i2]; prm[384 + i2] = be0[i2];
        prm[512 + i2] = b1[i2]; prm[640 + i2] = g1[i2]; prm[768 + i2] = be1[i2];
        prm[896 + i2] = b2[i2]; prm[1024 + i2] = g2[i2]; prm[1152 + i2] = be2[i2];
    }
    for (int i2 = t; i2 < 2048; i2 += 256) {
        int n = i2 >> 7, k = i2 & 127;
        wqT[i2] = (n < 4) ? (_Float16)wqk[k * 4 + n] : (_Float16)0.f;
    }
    for (int i2 = t; i2 < 16384; i2 += 256) {   // W1^T -> hS (f16)
        int k = i2 >> 7, n = i2 & 127;
        hS[n * 136 + k] = (_Float16)W1g[i2];
    }
    __syncthreads();
    // B-fragments of W1 (named scalars -> guaranteed VGPR residency)
    v8h B1_00 = *(const v8h*)&hS[(wv * 32 + l15) * 136 +  0 + quad * 8];
    v8h B1_01 = *(const v8h*)&hS[(wv * 32 + l15) * 136 + 32 + quad * 8];
    v8h B1_02 = *(const v8h*)&hS[(wv * 32 + l15) * 136 + 64 + quad * 8];
    v8h B1_03 = *(const v8h*)&hS[(wv * 32 + l15) * 136 + 96 + quad * 8];
    v8h B1_10 = *(const v8h*)&hS[(wv * 32 + 16 + l15) * 136 +  0 + quad * 8];
    v8h B1_11 = *(const v8h*)&hS[(wv * 32 + 16 + l15) * 136 + 32 + quad * 8];
    v8h B1_12 = *(const v8h*)&hS[(wv * 32 + 16 + l15) * 136 + 64 + quad * 8];
    v8h B1_13 = *(const v8h*)&hS[(wv * 32 + 16 + l15) * 136 + 96 + quad * 8];
    v8h WQ_0 = *(const v8h*)&wqT[l15 * 128 +  0 + quad * 8];
    v8h WQ_1 = *(const v8h*)&wqT[l15 * 128 + 32 + quad * 8];
    v8h WQ_2 = *(const v8h*)&wqT[l15 * 128 + 64 + quad * 8];
    v8h WQ_3 = *(const v8h*)&wqT[l15 * 128 + 96 + quad * 8];
    const float bs1a = prm[512 + col0], bs1b = prm[512 + col1];
    const float gg1a = prm[640 + col0], gg1b = prm[640 + col1];
    const float bb1a = prm[768 + col0], bb1b = prm[768 + col1];
    const float bs2a = prm[896 + col0], bs2b = prm[896 + col1];
    const float gg2a = prm[1024 + col0], gg2b = prm[1024 + col1];
    const float bb2a = prm[1152 + col0], bb2b = prm[1152 + col1];
    const float bq = (l15 < 4) ? bqk[l15] : 0.f;
    __syncthreads();
    for (int i2 = t; i2 < 16384; i2 += 256) {   // W2^T -> hS (f16)
        int k = i2 >> 7, n = i2 & 127;
        hS[n * 136 + k] = (_Float16)W2g[i2];
    }
    __syncthreads();
    v8h B2_00 = *(const v8h*)&hS[(wv * 32 + l15) * 136 +  0 + quad * 8];
    v8h B2_01 = *(const v8h*)&hS[(wv * 32 + l15) * 136 + 32 + quad * 8];
    v8h B2_02 = *(const v8h*)&hS[(wv * 32 + l15) * 136 + 64 + quad * 8];
    v8h B2_03 = *(const v8h*)&hS[(wv * 32 + l15) * 136 + 96 + quad * 8];
    v8h B2_10 = *(const v8h*)&hS[(wv * 32 + 16 + l15) * 136 +  0 + quad * 8];
    v8h B2_11 = *(const v8h*)&hS[(wv * 32 + 16 + l15) * 136 + 32 + quad * 8];
    v8h B2_12 = *(const v8h*)&hS[(wv * 32 + 16 + l15) * 136 + 64 + quad * 8];
    v8h B2_13 = *(const v8h*)&hS[(wv * 32 + 16 + l15) * 136 + 96 + quad * 8];
    __syncthreads();

    const int TILES = (B_ * N_ * N_) / 128;   // 2304
    for (int tile = blockIdx.x; tile < TILES; tile += gridDim.x) {
        const int P0 = tile * 128;
        const int bb = P0 / (N_ * N_);
        const int rr = P0 - bb * (N_ * N_);
        const int ii = rr / N_;
        const int j0 = rr - ii * N_;          // 128 | 384 so (bb, ii) fixed per tile
        if (t < 128) {
            float dx = coors[(bb * N_ + ii) * 3 + 0] - coors[(bb * N_ + j0 + t) * 3 + 0];
            float dy = coors[(bb * N_ + ii) * 3 + 1] - coors[(bb * N_ + j0 + t) * 3 + 1];
            float dz = coors[(bb * N_ + ii) * 3 + 2] - coors[(bb * N_ + j0 + t) * 3 + 2];
            distS[t] = sqrtf(dx * dx + dy * dy + dz * dz);
        }
        __syncthreads();
        {   // layer0: h0[c] = silu(ln(dist*w0[c]+b0[c])) — 2 threads/row
            const int row = t >> 1, cb = (t & 1) << 6;
            float dist = distS[row];
            float s = 0.f, sq = 0.f;
            for (int ci = 0; ci < 64; ci++) {
                float vx = dist * prm[cb + ci] + prm[128 + cb + ci];
                s += vx; sq += vx * vx;
            }
            s += __shfl_xor(s, 1); sq += __shfl_xor(sq, 1);
            float mean = s * (1.f / 128.f);
            float inv = rsqrtf(sq * (1.f / 128.f) - mean * mean + 1e-5f);
            _Float16* hp = &hS[row * 136 + cb];
            for (int c8 = 0; c8 < 64; c8 += 8) {
                v8h o;
                #pragma unroll
                for (int jj = 0; jj < 8; jj++) {
                    int c = cb + c8 + jj;
                    float vx = dist * prm[c] + prm[128 + c];
                    float y = (vx - mean) * inv * prm[256 + c] + prm[384 + c];
                    o[jj] = (_Float16)(y / (1.f + __expf(-y)));
                }
                *(v8h*)&hp[c8] = o;
            }
        }
        __syncthreads();

        DO_LAYER(B1, bs1a, bs1b, gg1a, gg1b, bb1a, bb1b)
        DO_LAYER(B2, bs2a, bs2b, gg2a, gg2b, bb2a, bb2b)

        // p store: coalesced 16B per thread
        #pragma unroll
        for (int it = 0; it < 8; it++) {
            int Lx = it * 2048 + t * 8;
            int row = Lx >> 7, cc = Lx & 127;
            *(v8h*)&pout[(long)(P0 + row) * 128 + cc] = *(const v8h*)&hS[row * 136 + cc];
        }
        // qk_pos = p @ wqk + bqk via mini-MFMA (each wave: 2 m-tiles)
        #pragma unroll
        for (int m2 = 0; m2 < 2; m2++) {
            int mt = wv * 2 + m2;
            const _Float16* hr = &hS[(mt * 16 + l15) * 136 + quad * 8];
            v8h a0 = *(const v8h*)&hr[0];
            v8h a1 = *(const v8h*)&hr[32];
            v8h a2 = *(const v8h*)&hr[64];
            v8h a3 = *(const v8h*)&hr[96];
            v4f c = {0.f, 0.f, 0.f, 0.f};
            c = __builtin_amdgcn_mfma_f32_16x16x32_f16(a0, WQ_0, c, 0, 0, 0);
            c = __builtin_amdgcn_mfma_f32_16x16x32_f16(a1, WQ_1, c, 0, 0, 0);
            c = __builtin_amdgcn_mfma_f32_16x16x32_f16(a2, WQ_2, c, 0, 0, 0);
            c = __builtin_amdgcn_mfma_f32_16x16x32_f16(a3, WQ_3, c, 0, 0, 0);
            if (l15 < 4) {
                #pragma unroll
                for (int rg2 = 0; rg2 < 4; rg2++) {
                    int row = mt * 16 + quad * 4 + rg2;
                    qkpos[(long)(P0 + row) * 4 + l15] = c[rg2] + bq;
                }
            }
        }
        __syncthreads();
    }
}

// ---------- K3M: fused scores/edge-MLP/softmax/coor-branch/ap/attn@v/out-proj ----------
// One block per (b,i), 384 threads (one per j).
__global__ __launch_bounds__(384) void eq_k3m(
    const float* __restrict__ q, const float* __restrict__ kT,
    const float* __restrict__ edges, const float* __restrict__ qkpos,
    const _Float16* __restrict__ p, const float* __restrict__ v,
    const float* __restrict__ coors,
    const float* __restrict__ w_e1, const float* __restrict__ w_e2,
    const float* __restrict__ w_c, const float* __restrict__ w_cg,
    const float* __restrict__ b_cg, const float* __restrict__ w_th,
    const float* __restrict__ cscale, const float* __restrict__ ccomb,
    const float* __restrict__ og, const float* __restrict__ rg,
    const float* __restrict__ w_vpos, const float* __restrict__ b_vpos,
    const float* __restrict__ w_out, const float* __restrict__ b_out,
    float* __restrict__ out0, float* __restrict__ out1) {
    int row = blockIdx.x;           // b*N + i
    int b = row / N_, i = row - b * N_;
    int j = threadIdx.x;            // 0..383
    __shared__ float qs[H_ * DH_];
    __shared__ float we1[20 * 40];
    __shared__ float we2[40 * 4];
    __shared__ float wcs[16], wcgs[16], bcgs[4], wths[16];
    __shared__ float attnS[4 * N_];
    __shared__ float apS[4 * PD_];
    __shared__ float nodeS[256];
    __shared__ float4 red4[16];

    if (j < 256) qs[j] = q[((b * H_ + (j >> 6)) * N_ + i) * DH_ + (j & 63)];
    for (int idx = j; idx < 800; idx += 384) we1[idx] = w_e1[idx];
    if (j < 160) we2[j] = w_e2[j];
    if (j < 16) { wcs[j] = w_c[j]; wcgs[j] = w_cg[j]; wths[j] = w_th[j]; }
    if (j < 4) bcgs[j] = b_cg[j];
    __syncthreads();

    // ---- phase A: scores + edge MLP (per j) ----
    long pair = ((long)row) * N_ + j;
    float in20[20];
    #pragma unroll
    for (int h = 0; h < H_; h++) {
        float acc = 0;
        const float* kp = kT + ((long)(b * H_ + h) * DH_) * N_ + j;
        #pragma unroll 8
        for (int d = 0; d < DH_; d++) acc += qs[h * DH_ + d] * kp[(long)d * N_];
        in20[h] = acc;
    }
    {
        float4 qp = *(const float4*)(qkpos + pair * 4);
        in20[0] += qp.x; in20[1] += qp.y; in20[2] += qp.z; in20[3] += qp.w;
    }
    const float4* ep = (const float4*)(edges + pair * ED_);
    float4 e0 = ep[0], e1 = ep[1], e2 = ep[2], e3 = ep[3];
    in20[4] = e0.x;  in20[5] = e0.y;  in20[6] = e0.z;  in20[7] = e0.w;
    in20[8] = e1.x;  in20[9] = e1.y;  in20[10] = e1.z; in20[11] = e1.w;
    in20[12] = e2.x; in20[13] = e2.y; in20[14] = e2.z; in20[15] = e2.w;
    in20[16] = e3.x; in20[17] = e3.y; in20[18] = e3.z; in20[19] = e3.w;

    float c0 = 0, c1 = 0, c2 = 0, c3 = 0;
    for (int o = 0; o < 40; o++) {
        float a = 0;
        #pragma unroll
        for (int c = 0; c < 20; c++) a += in20[c] * we1[c * 40 + o];
        float gg = gelu_(a);
        c0 += gg * we2[o * 4 + 0]; c1 += gg * we2[o * 4 + 1];
        c2 += gg * we2[o * 4 + 2]; c3 += gg * we2[o * 4 + 3];
    }
    float cmi[4] = {c0, c1, c2, c3};
    float gc[4], cp[4], rs[4];
    #pragma unroll
    for (int h = 0; h < 4; h++) gc[h] = gelu_(cmi[h]);
    #pragma unroll
    for (int h = 0; h < 4; h++) {
        cp[h] = gc[0] * wcs[h] + gc[1] * wcs[4 + h] + gc[2] * wcs[8 + h] + gc[3] * wcs[12 + h];
        rs[h] = cmi[0] * wcgs[h] + cmi[1] * wcgs[4 + h] + cmi[2] * wcgs[8 + h] + cmi[3] * wcgs[12 + h] + bcgs[h];
    }

    // ---- phase B: softmax over j + talking heads -> attnS ----
    float4 m4 = block_reduce4(make_float4(cmi[0], cmi[1], cmi[2], cmi[3]), true, red4, 0);
    float e[4];
    e[0] = __expf(cmi[0] - m4.x); e[1] = __expf(cmi[1] - m4.y);
    e[2] = __expf(cmi[2] - m4.z); e[3] = __expf(cmi[3] - m4.w);
    float4 l4 = block_reduce4(make_float4(e[0], e[1], e[2], e[3]), false, red4, 1);
    float sm[4] = {e[0] / l4.x, e[1] / l4.y, e[2] / l4.z, e[3] / l4.w};
    #pragma unroll
    for (int h = 0; h < 4; h++)
        attnS[h * N_ + j] = wths[h * 4 + 0] * sm[0] + wths[h * 4 + 1] * sm[1]
                          + wths[h * 4 + 2] * sm[2] + wths[h * 4 + 3] * sm[3];

    // ---- phase C: coordinate branch -> out1 ----
    float dx = coors[(b * N_ + i) * 3 + 0] - coors[(b * N_ + j) * 3 + 0];
    float dy = coors[(b * N_ + i) * 3 + 1] - coors[(b * N_ + j) * 3 + 1];
    float dz = coors[(b * N_ + i) * 3 + 2] - coors[(b * N_ + j) * 3 + 2];
    float nrm = sqrtf(dx * dx + dy * dy + dz * dz);
    float sc = cscale[0] / fmaxf(nrm, 1e-8f);
    float rx = dx * sc, ry = dy * sc, rz = dz * sc;
    float4 cm4 = block_reduce4(make_float4(cp[0], cp[1], cp[2], cp[3]), true, red4, 0);
    float ec[4];
    ec[0] = __expf(cp[0] - cm4.x); ec[1] = __expf(cp[1] - cm4.y);
    ec[2] = __expf(cp[2] - cm4.z); ec[3] = __expf(cp[3] - cm4.w);
    float4 cl4 = block_reduce4(make_float4(ec[0], ec[1], ec[2], ec[3]), false, red4, 1);
    float w[4] = {ec[0] / cl4.x * rs[0], ec[1] / cl4.y * rs[1],
                  ec[2] / cl4.z * rs[2], ec[3] / cl4.w * rs[3]};
    float4 sx4 = block_reduce4(make_float4(w[0] * rx, w[1] * rx, w[2] * rx, w[3] * rx), false, red4, 0);
    float4 sy4 = block_reduce4(make_float4(w[0] * ry, w[1] * ry, w[2] * ry, w[3] * ry), false, red4, 1);
    float4 sz4 = block_reduce4(make_float4(w[0] * rz, w[1] * rz, w[2] * rz, w[3] * rz), false, red4, 0);
    if (j == 0) {
        float f0 = ccomb[0] * rg[(b * H_ + 0) * N_ + i];
        float f1 = ccomb[1] * rg[(b * H_ + 1) * N_ + i];
        float f2 = ccomb[2] * rg[(b * H_ + 2) * N_ + i];
        float f3 = ccomb[3] * rg[(b * H_ + 3) * N_ + i];
        out1[(b * N_ + i) * 3 + 0] = f0 * sx4.x + f1 * sx4.y + f2 * sx4.z + f3 * sx4.w;
        out1[(b * N_ + i) * 3 + 1] = f0 * sy4.x + f1 * sy4.y + f2 * sy4.z + f3 * sy4.w;
        out1[(b * N_ + i) * 3 + 2] = f0 * sz4.x + f1 * sz4.y + f2 * sz4.z + f3 * sz4.w;
    }
    __syncthreads();   // attnS fully written (last reduce barrier covers most; this covers attnS stores)

    // ---- phase D: threads 0..127 -> ap; threads 128..383 -> attn@v ----
    if (j < 128) {
        float a0 = 0, a1 = 0, a2 = 0, a3 = 0;
        const _Float16* pp = p + ((long)row * N_) * PD_ + j;
        #pragma unroll 4
        for (int jj = 0; jj < N_; jj++) {
            float pv = (float)pp[(long)jj * PD_];
            a0 += attnS[jj] * pv;
            a1 += attnS[N_ + jj] * pv;
            a2 += attnS[2 * N_ + jj] * pv;
            a3 += attnS[3 * N_ + jj] * pv;
        }
        apS[j] = a0; apS[PD_ + j] = a1; apS[2 * PD_ + j] = a2; apS[3 * PD_ + j] = a3;
    } else {
        int tt = j - 128, h = tt >> 6, d = tt & 63;
        float acc = 0;
        const float* vp = v + ((long)(b * H_ + h) * N_) * DH_ + d;
        #pragma unroll 8
        for (int jj = 0; jj < N_; jj++) acc += attnS[h * N_ + jj] * vp[(long)jj * DH_];
        nodeS[tt] = acc;
    }
    __syncthreads();

    // ---- phase E: node = (attnv + ap@w_vpos + Sh*b_vpos) * out_gate ----
    float nv = 0;
    if (j < 256) {
        int h = j >> 6, d = j & 63;
        float accp = 0;
        const float* wv = w_vpos + h * DH_ + d;
        #pragma unroll 8
        for (int c = 0; c < PD_; c++) accp += apS[h * PD_ + c] * wv[(long)c * (H_ * DH_)];
        float Sh = wths[h * 4 + 0] + wths[h * 4 + 1] + wths[h * 4 + 2] + wths[h * 4 + 3];
        nv = (nodeS[j] + accp + Sh * b_vpos[h * DH_ + d]) * og[(b * H_ + h) * N_ + i];
    }
    __syncthreads();
    if (j < 256) nodeS[j] = nv;
    __syncthreads();

    // ---- phase F: out0 = node @ w_out + b_out ----
    if (j < 256) {
        float acc = b_out[j];
        #pragma unroll 8
        for (int c = 0; c < 256; c++) acc += nodeS[c] * w_out[(long)c * 256 + j];
        out0[(long)row * 256 + j] = acc;
    }
}

extern "C" void kernel_launch(void* const* d_in, const int* in_sizes, int n_in,
                              void* d_out, int out_size, void* d_ws, size_t ws_size,
                              hipStream_t stream) {
    (void)in_sizes; (void)n_in; (void)out_size; (void)ws_size;
    const float* feats   = (const float*)d_in[0];
    const float* coors   = (const float*)d_in[1];
    const float* edges   = (const float*)d_in[2];
    const float* gamma   = (const float*)d_in[3];
    const float* w_qkv   = (const float*)d_in[4];
    const float* w_gate  = (const float*)d_in[5];
    const float* b_gate  = (const float*)d_in[6];
    const float* w_th    = (const float*)d_in[7];
    const float* w_e1    = (const float*)d_in[8];
    const float* w_e2    = (const float*)d_in[9];
    const float* w_c     = (const float*)d_in[10];
    const float* w_cg    = (const float*)d_in[11];
    const float* b_cg    = (const float*)d_in[12];
    const float* cscale  = (const float*)d_in[13];
    const float* ccomb   = (const float*)d_in[14];
    const float* pb_w0   = (const float*)d_in[15];
    const float* pb_b0   = (const float*)d_in[16];
    const float* pb_g0   = (const float*)d_in[17];
    const float* pb_be0  = (const float*)d_in[18];
    const float* pb_w1   = (const float*)d_in[19];
    const float* pb_b1   = (const float*)d_in[20];
    const float* pb_g1   = (const float*)d_in[21];
    const float* pb_be1  = (const float*)d_in[22];
    const float* pb_w2   = (const float*)d_in[23];
    const float* pb_b2   = (const float*)d_in[24];
    const float* pb_g2   = (const float*)d_in[25];
    const float* pb_be2  = (const float*)d_in[26];
    const float* w_qkpos = (const float*)d_in[27];
    const float* b_qkpos = (const float*)d_in[28];
    const float* w_vpos  = (const float*)d_in[29];
    const float* b_vpos  = (const float*)d_in[30];
    const float* w_out   = (const float*)d_in[31];
    const float* b_out   = (const float*)d_in[32];

    // workspace carve (floats)
    float* wsf    = (float*)d_ws;
    float* q      = wsf;                    // 196608
    float* kT     = q      + 196608;        // 196608
    float* v      = kT     + 196608;        // 196608
    float* og     = v      + 196608;        // 3072
    float* rg     = og     + 3072;          // 3072
    float* qkpos  = rg     + 3072;          // 1179648 (b,i,j,h)
    _Float16* pbuf = (_Float16*)(qkpos + 1179648);  // 37748736 f16

    float* out0 = (float*)d_out;
    float* out1 = out0 + (long)B_ * N_ * DIM_;

    eq_k1<<<B_ * N_, 256, 0, stream>>>(feats, gamma, w_qkv, w_gate, b_gate, q, kT, v, og, rg);
    eq_k2<<<512, 256, 0, stream>>>(coors, pb_w0, pb_b0, pb_g0, pb_be0,
                                   pb_w1, pb_b1, pb_g1, pb_be1,
                                   pb_w2, pb_b2, pb_g2, pb_be2,
                                   w_qkpos, b_qkpos, pbuf, qkpos);
    eq_k3m<<<B_ * N_, 384, 0, stream>>>(q, kT, edges, qkpos, pbuf, v, coors,
                                        w_e1, w_e2, w_c, w_cg, b_cg, w_th,
                                        cscale, ccomb, og, rg,
                                        w_vpos, b_vpos, w_out, b_out, out0, out1);
}